// Round 7
// baseline (379.520 us; speedup 1.0000x reference)
//
#include <hip/hip_runtime.h>
#include <hip/hip_bf16.h>

#define N_EMBD 768
#define N_HEADS 12
#define HEAD_DIM 64

typedef __attribute__((ext_vector_type(4))) float f32x4;
typedef __attribute__((ext_vector_type(8))) short s16x8;

__device__ __forceinline__ float bf2f(unsigned short u) {
  union { unsigned int i; float f; } z;
  z.i = ((unsigned int)u) << 16;
  return z.f;
}

__device__ __forceinline__ void gload_lds16(const void* g, void* l) {
  __builtin_amdgcn_global_load_lds(
      (const __attribute__((address_space(1))) void*)g,
      (__attribute__((address_space(3))) void*)l, 16, 0, 0);
}

__device__ __forceinline__ float gelu_f(float x) {
  const float c = 0.7978845608028654f;
  float u = c * (x + 0.044715f * x * x * x);
  float t = 1.0f - 2.0f / (__expf(2.0f * u) + 1.0f);
  return 0.5f * x * (1.0f + t);
}

// ---------------- weight fp32 -> bf16 (all four in one launch) ----------------
__global__ void cvt4_kernel(const float* __restrict__ s0, __hip_bfloat16* d0,
                            const float* __restrict__ s1, __hip_bfloat16* d1,
                            const float* __restrict__ s2, __hip_bfloat16* d2,
                            const float* __restrict__ s3, __hip_bfloat16* d3,
                            int n0, int n1, int n2, int n3) {
  int i = blockIdx.x * 256 + threadIdx.x;
  if (i < n0) { d0[i] = __float2bfloat16(s0[i]); return; }
  i -= n0;
  if (i < n1) { d1[i] = __float2bfloat16(s1[i]); return; }
  i -= n1;
  if (i < n2) { d2[i] = __float2bfloat16(s2[i]); return; }
  i -= n2;
  if (i < n3) d3[i] = __float2bfloat16(s3[i]);
}

// ---------------- fused LayerNorm: fp32 in -> bf16 out ----------------
__global__ __launch_bounds__(256) void ln_kernel(
    const float* __restrict__ x, const float* __restrict__ g,
    const float* __restrict__ b, __hip_bfloat16* __restrict__ out) {
  __shared__ float red[8];
  const int row = blockIdx.x;
  const int tid = threadIdx.x;
  const float* xr = x + (size_t)row * N_EMBD;
  float v0 = xr[tid], v1 = xr[tid + 256], v2 = xr[tid + 512];
  float s = v0 + v1 + v2;
#pragma unroll
  for (int m = 32; m >= 1; m >>= 1) s += __shfl_xor(s, m);
  if ((tid & 63) == 0) red[tid >> 6] = s;
  __syncthreads();
  float mu = (red[0] + red[1] + red[2] + red[3]) * (1.0f / 768.0f);
  float d0 = v0 - mu, d1 = v1 - mu, d2 = v2 - mu;
  float ss = d0 * d0 + d1 * d1 + d2 * d2;
  __syncthreads();
#pragma unroll
  for (int m = 32; m >= 1; m >>= 1) ss += __shfl_xor(ss, m);
  if ((tid & 63) == 0) red[4 + (tid >> 6)] = ss;
  __syncthreads();
  float var = (red[4] + red[5] + red[6] + red[7]) * (1.0f / 768.0f);
  float rstd = rsqrtf(var + 1e-5f);
  __hip_bfloat16* orow = out + (size_t)row * N_EMBD;
  orow[tid]       = __float2bfloat16(d0 * rstd * g[tid]       + b[tid]);
  orow[tid + 256] = __float2bfloat16(d1 * rstd * g[tid + 256] + b[tid + 256]);
  orow[tid + 512] = __float2bfloat16(d2 * rstd * g[tid + 512] + b[tid + 512]);
}

// ---------------- bf16 MFMA GEMM: C[M,N] = A[M,K] * W[N,K]^T + bias ----------------
// 2-phase double-buffered + chunked XCD-aware block swizzle.
#define TILE_M 128
#define TILE_N 128
#define TILE_K 32

template <int EPI>
__global__ __launch_bounds__(256) void gemm_bt(
    const __hip_bfloat16* __restrict__ A, const __hip_bfloat16* __restrict__ W,
    const float* __restrict__ bias, const float* __restrict__ resid,
    __hip_bfloat16* __restrict__ outb, float* __restrict__ outf,
    int M, int N, int K) {
  __shared__ __hip_bfloat16 smA[2][TILE_M * TILE_K];
  __shared__ __hip_bfloat16 smB[2][TILE_N * TILE_K];
  const int tid = threadIdx.x;
  const int lane = tid & 63;
  const int wave = tid >> 6;

  // chunked XCD swizzle: consecutive virt ids (same A-panel) share an XCD L2
  const int nbx = gridDim.x;
  const int nwg = nbx * gridDim.y;
  int bid = blockIdx.y * nbx + blockIdx.x;
  if ((nwg & 7) == 0) bid = (bid & 7) * (nwg >> 3) + (bid >> 3);
  const int m0 = (bid / nbx) * TILE_M;
  const int n0 = (bid % nbx) * TILE_N;
  const int wr = wave >> 1, wc = wave & 1;

  f32x4 acc[4][4];
#pragma unroll
  for (int i = 0; i < 4; ++i)
#pragma unroll
    for (int j = 0; j < 4; ++j) acc[i][j] = f32x4{0.f, 0.f, 0.f, 0.f};

  const int ar0 = tid >> 2;
  const int ac0 = (tid & 3) * 8;
  const __hip_bfloat16* Abase0 = A + (size_t)(m0 + ar0) * K + ac0;
  const __hip_bfloat16* Abase1 = A + (size_t)(m0 + 64 + ar0) * K + ac0;
  const __hip_bfloat16* Wbase0 = W + (size_t)(n0 + ar0) * K + ac0;
  const __hip_bfloat16* Wbase1 = W + (size_t)(n0 + 64 + ar0) * K + ac0;

  auto stage = [&](int buf, int k0) {
    gload_lds16(Abase0 + k0, &smA[buf][wave * 512]);
    gload_lds16(Abase1 + k0, &smA[buf][2048 + wave * 512]);
    gload_lds16(Wbase0 + k0, &smB[buf][wave * 512]);
    gload_lds16(Wbase1 + k0, &smB[buf][2048 + wave * 512]);
  };

  const int rA = lane & 15;
  const int ko = (lane >> 4) * 8;
  const int nk = K / TILE_K;

  stage(0, 0);
  __syncthreads();

  int cur = 0;
  for (int t = 0; t < nk; ++t) {
    if (t + 1 < nk) stage(cur ^ 1, (t + 1) * TILE_K);

    s16x8 af[4], bfr[4];
#pragma unroll
    for (int mi = 0; mi < 4; ++mi)
      af[mi] = *(const s16x8*)&smA[cur][(wr * 64 + mi * 16 + rA) * TILE_K + ko];
#pragma unroll
    for (int ni = 0; ni < 4; ++ni)
      bfr[ni] = *(const s16x8*)&smB[cur][(wc * 64 + ni * 16 + rA) * TILE_K + ko];
#pragma unroll
    for (int mi = 0; mi < 4; ++mi)
#pragma unroll
      for (int ni = 0; ni < 4; ++ni)
        acc[mi][ni] = __builtin_amdgcn_mfma_f32_16x16x32_bf16(
            af[mi], bfr[ni], acc[mi][ni], 0, 0, 0);

    __syncthreads();
    cur ^= 1;
  }

  const int crow = (lane >> 4) * 4;
  const int ccol = lane & 15;
#pragma unroll
  for (int mi = 0; mi < 4; ++mi) {
#pragma unroll
    for (int ni = 0; ni < 4; ++ni) {
      const int col = n0 + wc * 64 + ni * 16 + ccol;
      const float bv = bias[col];
#pragma unroll
      for (int j = 0; j < 4; ++j) {
        const int row = m0 + wr * 64 + mi * 16 + crow + j;
        float v = acc[mi][ni][j] + bv;
        const size_t o = (size_t)row * N + col;
        if (EPI == 0) {
          outb[o] = __float2bfloat16(v);
        } else if (EPI == 1) {
          outb[o] = __float2bfloat16(gelu_f(v));
        } else {
          outf[o] = resid[o] + v;
        }
      }
    }
  }
}

// ---------------- MFMA causal flash attention ----------------
// Paired q-tiles (perfect balance), double-buffered K/V LDS:
//   K: global_load_lds direct into linear [64][64] + XOR swizzle (both sides)
//   V: reg-prefetch issued before process(), swizzled V^T write after barrier
//   P: linear [16][64] per wave + same swizzle
// XOR swizzle: byte ^= (row&7)<<4  (row = byte>>7; 128B rows).
__global__ __launch_bounds__(256) void attn_mfma(
    const __hip_bfloat16* __restrict__ qkv, __hip_bfloat16* __restrict__ y,
    int T) {
  __shared__ __align__(16) char ksm[2][8192];   // K  [key][d] swizzled
  __shared__ __align__(16) char vtm[2][8192];   // V^T [d][key] swizzled
  __shared__ __align__(16) char psm[4][2048];   // per-wave P [q][key] swizzled
  const int tid = threadIdx.x;
  const int lane = tid & 63;
  const int wave = tid >> 6;

  // chunked XCD swizzle (768 = 96*8): same-bh blocks share an XCD L2
  const int nbx = gridDim.x;  // 16
  const int nwg = nbx * gridDim.y;
  int bid = blockIdx.y * nbx + blockIdx.x;
  if ((nwg & 7) == 0) bid = (bid & 7) * (nwg >> 3) + (bid >> 3);
  const int bx = bid % nbx;
  const int bh = bid / nbx;
  const int b = bh / N_HEADS, h = bh % N_HEADS;

  const int nq = T / 64;
  const int qa0 = bx * 64;             // early q-tile
  const int qb0 = (nq - 1 - bx) * 64;  // late q-tile
  const size_t ldq = 3 * N_EMBD;
  const __hip_bfloat16* qb_ = qkv + (size_t)b * T * ldq + h * HEAD_DIM;
  const __hip_bfloat16* kb = qb_ + N_EMBD;
  const __hip_bfloat16* vb = qb_ + 2 * N_EMBD;

  const int fr = lane & 15;          // fragment row/col index
  const int fo = (lane >> 4) * 8;    // fragment k-offset (elems)
  const int g16 = fo * 2;            // byte offset of fragment col-block
  const int crow = (lane >> 4) * 4;  // C/D row base

  // prescale Q by 1/sqrt(D) * log2(e) so softmax uses native exp2
  const float qs = 0.125f * 1.44269504f;
  auto loadq = [&](int qrow, int o) -> s16x8 {
    s16x8 v = *(const s16x8*)(qb_ + (size_t)qrow * ldq + o);
    s16x8 r;
#pragma unroll
    for (int i = 0; i < 8; ++i) {
      float f = bf2f((unsigned short)v[i]) * qs;
      __hip_bfloat16 hb = __float2bfloat16(f);
      r[i] = *reinterpret_cast<short*>(&hb);
    }
    return r;
  };
  s16x8 qfa0 = loadq(qa0 + wave * 16 + fr, fo);
  s16x8 qfa1 = loadq(qa0 + wave * 16 + fr, fo + 32);
  s16x8 qfb0 = loadq(qb0 + wave * 16 + fr, fo);
  s16x8 qfb1 = loadq(qb0 + wave * 16 + fr, fo + 32);

  f32x4 oa[4], ob[4];
  float ma[4], la[4], mb[4], lb_[4];
#pragma unroll
  for (int j = 0; j < 4; ++j) {
    oa[j] = f32x4{0.f, 0.f, 0.f, 0.f};
    ob[j] = f32x4{0.f, 0.f, 0.f, 0.f};
    ma[j] = -1e30f; la[j] = 0.f; mb[j] = -1e30f; lb_[j] = 0.f;
  }

  // ---- K staging via global_load_lds: linear dest + pre-swizzled source ----
  // lane l writes LDS granule (row = r0+(l>>3), c = l&7); source chunk c^(l>>3)
  const int krowoff = lane >> 3;                 // 0..7
  const int kcx = ((lane & 7) ^ (lane >> 3)) * 8;  // source col elems
  auto issueK = [&](int kt, int bufi) {
#pragma unroll
    for (int j = 0; j < 2; ++j) {
      const int r0 = (wave * 2 + j) * 8;
      gload_lds16(kb + (size_t)(kt + r0 + krowoff) * ldq + kcx,
                  ksm[bufi] + r0 * 128);
    }
  };

  // ---- V prefetch regs + swizzled V^T write ----
  s16x8 vr0, vr1;
  auto loadV = [&](int kt) {
    const __hip_bfloat16* vrow = vb + (size_t)(kt + lane) * ldq + wave * 16;
    vr0 = *(const s16x8*)(vrow);
    vr1 = *(const s16x8*)(vrow + 8);
  };
  auto writeV = [&](int bufi) {
    char* base = vtm[bufi];
#pragma unroll
    for (int i = 0; i < 8; ++i) {
      const int d = wave * 16 + i;
      *(short*)(base + ((d * 128 + lane * 2) ^ ((d & 7) << 4))) = vr0[i];
    }
#pragma unroll
    for (int i = 0; i < 8; ++i) {
      const int d = wave * 16 + 8 + i;
      *(short*)(base + ((d * 128 + lane * 2) ^ ((d & 7) << 4))) = vr1[i];
    }
  };

  char* psb = psm[wave];

  auto process = [&](const char* ksb, const char* vtb, const s16x8& q0f,
                     const s16x8& q1f, f32x4 (&o)[4], float (&m_)[4],
                     float (&l_)[4], int tq0, bool diag, int kt) {
    // QK^T: S[16q x 64k], C/D layout col=key (fr), row=q (crow+j)
    f32x4 sv[4];
#pragma unroll
    for (int sub = 0; sub < 4; ++sub) {
      const int krow = sub * 16 + fr;
      const int kswz = (krow & 7) << 4;
      s16x8 b0 = *(const s16x8*)(ksb + ((krow * 128 + g16) ^ kswz));
      s16x8 b1 = *(const s16x8*)(ksb + ((krow * 128 + g16 + 64) ^ kswz));
      f32x4 acc = f32x4{0.f, 0.f, 0.f, 0.f};
      acc = __builtin_amdgcn_mfma_f32_16x16x32_bf16(q0f, b0, acc, 0, 0, 0);
      acc = __builtin_amdgcn_mfma_f32_16x16x32_bf16(q1f, b1, acc, 0, 0, 0);
      sv[sub] = acc;
    }
    if (diag) {
      const int wq0 = tq0 + wave * 16;
#pragma unroll
      for (int sub = 0; sub < 4; ++sub) {
        const int key = kt + sub * 16 + fr;
#pragma unroll
        for (int j = 0; j < 4; ++j)
          if (key > wq0 + crow + j) sv[sub][j] = -1e30f;
      }
    }
    // online softmax with defer-max (T13, THR=8 in exp2 units)
    float corr[4];
    bool r0f, r1f, r2f, r3f;
#pragma unroll
    for (int j = 0; j < 4; ++j) {
      float t = fmaxf(fmaxf(sv[0][j], sv[1][j]), fmaxf(sv[2][j], sv[3][j]));
#pragma unroll
      for (int msk = 1; msk <= 8; msk <<= 1) t = fmaxf(t, __shfl_xor(t, msk));
      bool resc = t > m_[j] + 8.0f;
      corr[j] = resc ? exp2f(m_[j] - t) : 1.0f;
      if (resc) m_[j] = t;
      if (j == 0) r0f = resc; else if (j == 1) r1f = resc;
      else if (j == 2) r2f = resc; else r3f = resc;
    }
    float rs[4] = {0.f, 0.f, 0.f, 0.f};
#pragma unroll
    for (int sub = 0; sub < 4; ++sub) {
#pragma unroll
      for (int j = 0; j < 4; ++j) {
        float p = exp2f(sv[sub][j] - m_[j]);
        rs[j] += p;
        __hip_bfloat16 hb = __float2bfloat16(p);
        const int q = crow + j;
        *(short*)(psb + ((q * 128 + (sub * 16 + fr) * 2) ^ ((q & 7) << 4))) =
            *reinterpret_cast<short*>(&hb);
      }
    }
#pragma unroll
    for (int j = 0; j < 4; ++j) {
#pragma unroll
      for (int msk = 1; msk <= 8; msk <<= 1) rs[j] += __shfl_xor(rs[j], msk);
      l_[j] = l_[j] * corr[j] + rs[j];
    }
    if (__any(r0f || r1f || r2f || r3f)) {
#pragma unroll
      for (int ds = 0; ds < 4; ++ds)
#pragma unroll
        for (int j = 0; j < 4; ++j) o[ds][j] *= corr[j];
    }
    const int fswz = (fr & 7) << 4;
    s16x8 pf0 = *(const s16x8*)(psb + ((fr * 128 + g16) ^ fswz));
    s16x8 pf1 = *(const s16x8*)(psb + ((fr * 128 + g16 + 64) ^ fswz));
#pragma unroll
    for (int ds = 0; ds < 4; ++ds) {
      const int vrow = ds * 16 + fr;
      const int vswz = (vrow & 7) << 4;
      s16x8 v0 = *(const s16x8*)(vtb + ((vrow * 128 + g16) ^ vswz));
      s16x8 v1 = *(const s16x8*)(vtb + ((vrow * 128 + g16 + 64) ^ vswz));
      o[ds] = __builtin_amdgcn_mfma_f32_16x16x32_bf16(pf0, v0, o[ds], 0, 0, 0);
      o[ds] = __builtin_amdgcn_mfma_f32_16x16x32_bf16(pf1, v1, o[ds], 0, 0, 0);
    }
  };

  // prologue: stage tile 0 into buf 0
  issueK(0, 0);
  loadV(0);
  __syncthreads();   // drains K-DMA + V loads
  writeV(0);
  __syncthreads();   // buf0 fully published

  int cur = 0;
  for (int kt = 0; kt <= qb0; kt += 64) {
    const bool hasnext = (kt + 64 <= qb0);
    if (hasnext) {
      issueK(kt + 64, cur ^ 1);  // DMA flies under process
      loadV(kt + 64);            // reg loads fly under process
    }
    if (kt <= qa0)
      process(ksm[cur], vtm[cur], qfa0, qfa1, oa, ma, la, qa0, kt == qa0, kt);
    process(ksm[cur], vtm[cur], qfb0, qfb1, ob, mb, lb_, qb0, kt == qb0, kt);
    __syncthreads();             // readers done; K-DMA drained into buf^1
    if (hasnext) writeV(cur ^ 1);
    __syncthreads();             // buf^1 fully published
    cur ^= 1;
  }

#pragma unroll
  for (int j = 0; j < 4; ++j) {
    const float inva = 1.0f / la[j];
    const float invb = 1.0f / lb_[j];
    __hip_bfloat16* ya =
        y + (size_t)(b * T + qa0 + wave * 16 + crow + j) * N_EMBD + h * HEAD_DIM;
    __hip_bfloat16* yb =
        y + (size_t)(b * T + qb0 + wave * 16 + crow + j) * N_EMBD + h * HEAD_DIM;
#pragma unroll
    for (int ds = 0; ds < 4; ++ds) {
      ya[ds * 16 + fr] = __float2bfloat16(oa[ds][j] * inva);
      yb[ds * 16 + fr] = __float2bfloat16(ob[ds][j] * invb);
    }
  }
}

// ---------------- launch ----------------
extern "C" void kernel_launch(void* const* d_in, const int* in_sizes, int n_in,
                              void* d_out, int out_size, void* d_ws,
                              size_t ws_size, hipStream_t stream) {
  const int B = 4, T = 2048, C = N_EMBD;
  const int M = B * T;  // 8192

  const float* x      = (const float*)d_in[0];
  const float* ln1_g  = (const float*)d_in[1];
  const float* ln1_b  = (const float*)d_in[2];
  const float* attn_w = (const float*)d_in[3];
  const float* attn_b = (const float*)d_in[4];
  const float* proj_w = (const float*)d_in[5];
  const float* proj_b = (const float*)d_in[6];
  const float* ln2_g  = (const float*)d_in[7];
  const float* ln2_b  = (const float*)d_in[8];
  const float* fc_w   = (const float*)d_in[9];
  const float* fc_b   = (const float*)d_in[10];
  const float* fc2_w  = (const float*)d_in[11];
  const float* fc2_b  = (const float*)d_in[12];
  float* out = (float*)d_out;

  char* p = (char*)d_ws;
  size_t off = 0;
  auto take = [&](size_t bytes) -> void* {
    void* q = p + off;
    off += (bytes + 1023) & ~(size_t)1023;
    return q;
  };

  __hip_bfloat16* wqkv  = (__hip_bfloat16*)take((size_t)3 * C * C * 2);
  __hip_bfloat16* wproj = (__hip_bfloat16*)take((size_t)C * C * 2);
  __hip_bfloat16* wfc   = (__hip_bfloat16*)take((size_t)4 * C * C * 2);
  __hip_bfloat16* wfc2  = (__hip_bfloat16*)take((size_t)4 * C * C * 2);
  __hip_bfloat16* hbuf  = (__hip_bfloat16*)take((size_t)M * C * 2);
  __hip_bfloat16* big   = (__hip_bfloat16*)take((size_t)M * 4 * C * 2);
  __hip_bfloat16* ybuf  = (__hip_bfloat16*)take((size_t)M * C * 2);
  float*          x1    = (float*)take((size_t)M * C * 4);

  {
    const int n0 = 3 * C * C, n1 = C * C, n2 = 4 * C * C, n3 = 4 * C * C;
    const int ntot = n0 + n1 + n2 + n3;  // 7,077,888 = 27648*256
    cvt4_kernel<<<(ntot + 255) / 256, 256, 0, stream>>>(
        attn_w, wqkv, proj_w, wproj, fc_w, wfc, fc2_w, wfc2, n0, n1, n2, n3);
  }

  ln_kernel<<<M, 256, 0, stream>>>(x, ln1_g, ln1_b, hbuf);
  gemm_bt<0><<<dim3(3 * C / TILE_N, M / TILE_M), 256, 0, stream>>>(
      hbuf, wqkv, attn_b, nullptr, big, nullptr, M, 3 * C, C);
  attn_mfma<<<dim3(T / 128, B * N_HEADS), 256, 0, stream>>>(big, ybuf, T);
  gemm_bt<2><<<dim3(C / TILE_N, M / TILE_M), 256, 0, stream>>>(
      ybuf, wproj, proj_b, x, nullptr, x1, M, C, C);
  ln_kernel<<<M, 256, 0, stream>>>(x1, ln2_g, ln2_b, hbuf);
  gemm_bt<1><<<dim3(4 * C / TILE_N, M / TILE_M), 256, 0, stream>>>(
      hbuf, wfc, fc_b, nullptr, big, nullptr, M, 4 * C, C);
  gemm_bt<2><<<dim3(C / TILE_N, M / TILE_M), 256, 0, stream>>>(
      big, wfc2, fc2_b, x1, nullptr, out, M, C, 4 * C);
}

// Round 8
// 339.170 us; speedup vs baseline: 1.1190x; 1.1190x over previous
//
#include <hip/hip_runtime.h>
#include <hip/hip_bf16.h>

#define N_EMBD 768
#define N_HEADS 12
#define HEAD_DIM 64

typedef __attribute__((ext_vector_type(4))) float f32x4;
typedef __attribute__((ext_vector_type(8))) short s16x8;

__device__ __forceinline__ float bf2f(unsigned short u) {
  union { unsigned int i; float f; } z;
  z.i = ((unsigned int)u) << 16;
  return z.f;
}

__device__ __forceinline__ void gload_lds16(const void* g, void* l) {
  __builtin_amdgcn_global_load_lds(
      (const __attribute__((address_space(1))) void*)g,
      (__attribute__((address_space(3))) void*)l, 16, 0, 0);
}

__device__ __forceinline__ float gelu_f(float x) {
  const float c = 0.7978845608028654f;
  float u = c * (x + 0.044715f * x * x * x);
  float t = 1.0f - 2.0f / (__expf(2.0f * u) + 1.0f);
  return 0.5f * x * (1.0f + t);
}

// ---------------- weight fp32 -> bf16 (all four in one launch) ----------------
__global__ void cvt4_kernel(const float* __restrict__ s0, __hip_bfloat16* d0,
                            const float* __restrict__ s1, __hip_bfloat16* d1,
                            const float* __restrict__ s2, __hip_bfloat16* d2,
                            const float* __restrict__ s3, __hip_bfloat16* d3,
                            int n0, int n1, int n2, int n3) {
  int i = blockIdx.x * 256 + threadIdx.x;
  if (i < n0) { d0[i] = __float2bfloat16(s0[i]); return; }
  i -= n0;
  if (i < n1) { d1[i] = __float2bfloat16(s1[i]); return; }
  i -= n1;
  if (i < n2) { d2[i] = __float2bfloat16(s2[i]); return; }
  i -= n2;
  if (i < n3) d3[i] = __float2bfloat16(s3[i]);
}

// ---------------- fused LayerNorm: fp32 in -> bf16 out ----------------
__global__ __launch_bounds__(256) void ln_kernel(
    const float* __restrict__ x, const float* __restrict__ g,
    const float* __restrict__ b, __hip_bfloat16* __restrict__ out) {
  __shared__ float red[8];
  const int row = blockIdx.x;
  const int tid = threadIdx.x;
  const float* xr = x + (size_t)row * N_EMBD;
  float v0 = xr[tid], v1 = xr[tid + 256], v2 = xr[tid + 512];
  float s = v0 + v1 + v2;
#pragma unroll
  for (int m = 32; m >= 1; m >>= 1) s += __shfl_xor(s, m);
  if ((tid & 63) == 0) red[tid >> 6] = s;
  __syncthreads();
  float mu = (red[0] + red[1] + red[2] + red[3]) * (1.0f / 768.0f);
  float d0 = v0 - mu, d1 = v1 - mu, d2 = v2 - mu;
  float ss = d0 * d0 + d1 * d1 + d2 * d2;
  __syncthreads();
#pragma unroll
  for (int m = 32; m >= 1; m >>= 1) ss += __shfl_xor(ss, m);
  if ((tid & 63) == 0) red[4 + (tid >> 6)] = ss;
  __syncthreads();
  float var = (red[4] + red[5] + red[6] + red[7]) * (1.0f / 768.0f);
  float rstd = rsqrtf(var + 1e-5f);
  __hip_bfloat16* orow = out + (size_t)row * N_EMBD;
  orow[tid]       = __float2bfloat16(d0 * rstd * g[tid]       + b[tid]);
  orow[tid + 256] = __float2bfloat16(d1 * rstd * g[tid + 256] + b[tid + 256]);
  orow[tid + 512] = __float2bfloat16(d2 * rstd * g[tid + 512] + b[tid + 512]);
}

// ---------------- bf16 MFMA GEMM: C[M,N] = A[M,K] * W[N,K]^T + bias ----------------
// 2-phase double-buffered + chunked XCD-aware block swizzle (R7-verified).
#define TILE_M 128
#define TILE_N 128
#define TILE_K 32

template <int EPI>
__global__ __launch_bounds__(256) void gemm_bt(
    const __hip_bfloat16* __restrict__ A, const __hip_bfloat16* __restrict__ W,
    const float* __restrict__ bias, const float* __restrict__ resid,
    __hip_bfloat16* __restrict__ outb, float* __restrict__ outf,
    int M, int N, int K) {
  __shared__ __hip_bfloat16 smA[2][TILE_M * TILE_K];
  __shared__ __hip_bfloat16 smB[2][TILE_N * TILE_K];
  const int tid = threadIdx.x;
  const int lane = tid & 63;
  const int wave = tid >> 6;

  // chunked XCD swizzle: consecutive virt ids (same A-panel) share an XCD L2
  const int nbx = gridDim.x;
  const int nwg = nbx * gridDim.y;
  int bid = blockIdx.y * nbx + blockIdx.x;
  if ((nwg & 7) == 0) bid = (bid & 7) * (nwg >> 3) + (bid >> 3);
  const int m0 = (bid / nbx) * TILE_M;
  const int n0 = (bid % nbx) * TILE_N;
  const int wr = wave >> 1, wc = wave & 1;

  f32x4 acc[4][4];
#pragma unroll
  for (int i = 0; i < 4; ++i)
#pragma unroll
    for (int j = 0; j < 4; ++j) acc[i][j] = f32x4{0.f, 0.f, 0.f, 0.f};

  const int ar0 = tid >> 2;
  const int ac0 = (tid & 3) * 8;
  const __hip_bfloat16* Abase0 = A + (size_t)(m0 + ar0) * K + ac0;
  const __hip_bfloat16* Abase1 = A + (size_t)(m0 + 64 + ar0) * K + ac0;
  const __hip_bfloat16* Wbase0 = W + (size_t)(n0 + ar0) * K + ac0;
  const __hip_bfloat16* Wbase1 = W + (size_t)(n0 + 64 + ar0) * K + ac0;

  auto stage = [&](int buf, int k0) {
    gload_lds16(Abase0 + k0, &smA[buf][wave * 512]);
    gload_lds16(Abase1 + k0, &smA[buf][2048 + wave * 512]);
    gload_lds16(Wbase0 + k0, &smB[buf][wave * 512]);
    gload_lds16(Wbase1 + k0, &smB[buf][2048 + wave * 512]);
  };

  const int rA = lane & 15;
  const int ko = (lane >> 4) * 8;
  const int nk = K / TILE_K;

  stage(0, 0);
  __syncthreads();

  int cur = 0;
  for (int t = 0; t < nk; ++t) {
    if (t + 1 < nk) stage(cur ^ 1, (t + 1) * TILE_K);

    s16x8 af[4], bfr[4];
#pragma unroll
    for (int mi = 0; mi < 4; ++mi)
      af[mi] = *(const s16x8*)&smA[cur][(wr * 64 + mi * 16 + rA) * TILE_K + ko];
#pragma unroll
    for (int ni = 0; ni < 4; ++ni)
      bfr[ni] = *(const s16x8*)&smB[cur][(wc * 64 + ni * 16 + rA) * TILE_K + ko];
#pragma unroll
    for (int mi = 0; mi < 4; ++mi)
#pragma unroll
      for (int ni = 0; ni < 4; ++ni)
        acc[mi][ni] = __builtin_amdgcn_mfma_f32_16x16x32_bf16(
            af[mi], bfr[ni], acc[mi][ni], 0, 0, 0);

    __syncthreads();
    cur ^= 1;
  }

  const int crow = (lane >> 4) * 4;
  const int ccol = lane & 15;
#pragma unroll
  for (int mi = 0; mi < 4; ++mi) {
#pragma unroll
    for (int ni = 0; ni < 4; ++ni) {
      const int col = n0 + wc * 64 + ni * 16 + ccol;
      const float bv = bias[col];
#pragma unroll
      for (int j = 0; j < 4; ++j) {
        const int row = m0 + wr * 64 + mi * 16 + crow + j;
        float v = acc[mi][ni][j] + bv;
        const size_t o = (size_t)row * N + col;
        if (EPI == 0) {
          outb[o] = __float2bfloat16(v);
        } else if (EPI == 1) {
          outb[o] = __float2bfloat16(gelu_f(v));
        } else {
          outf[o] = resid[o] + v;
        }
      }
    }
  }
}

// ---------------- MFMA causal flash attention, paired q-tiles ----------------
// R6-verified structure (136us). Single new variable vs R6: T13 defer-max
// (skip O-rescale when running max grows by <= 8 exp2-units).
#define AP 72

__global__ __launch_bounds__(256) void attn_mfma(
    const __hip_bfloat16* __restrict__ qkv, __hip_bfloat16* __restrict__ y,
    int T) {
  __shared__ __hip_bfloat16 ks[64 * AP];      // [key][d]
  __shared__ __hip_bfloat16 vt[64 * AP];      // [d][key]
  __shared__ __hip_bfloat16 ps[4][16 * AP];   // per-wave P [q][key]
  const int tid = threadIdx.x;
  const int lane = tid & 63;
  const int wave = tid >> 6;
  const int b = blockIdx.y / N_HEADS, h = blockIdx.y % N_HEADS;
  const int nq = T / 64;
  const int qa0 = blockIdx.x * 64;             // early tile
  const int qb0 = (nq - 1 - blockIdx.x) * 64;  // late tile
  const size_t ldq = 3 * N_EMBD;
  const __hip_bfloat16* qb_ = qkv + (size_t)b * T * ldq + h * HEAD_DIM;
  const __hip_bfloat16* kb = qb_ + N_EMBD;
  const __hip_bfloat16* vb = qb_ + 2 * N_EMBD;

  const int fr = lane & 15;          // fragment row/col index
  const int fo = (lane >> 4) * 8;    // fragment k-offset
  const int crow = (lane >> 4) * 4;  // C/D row base

  // prescale Q by 1/sqrt(D) * log2(e) so softmax uses native exp2
  const float qs = 0.125f * 1.44269504f;
  auto loadq = [&](int qrow, int o) -> s16x8 {
    s16x8 v = *(const s16x8*)(qb_ + (size_t)qrow * ldq + o);
    s16x8 r;
#pragma unroll
    for (int i = 0; i < 8; ++i) {
      float f = bf2f((unsigned short)v[i]) * qs;
      __hip_bfloat16 hb = __float2bfloat16(f);
      r[i] = *reinterpret_cast<short*>(&hb);
    }
    return r;
  };
  s16x8 qfa0 = loadq(qa0 + wave * 16 + fr, fo);
  s16x8 qfa1 = loadq(qa0 + wave * 16 + fr, fo + 32);
  s16x8 qfb0 = loadq(qb0 + wave * 16 + fr, fo);
  s16x8 qfb1 = loadq(qb0 + wave * 16 + fr, fo + 32);

  f32x4 oa[4], ob[4];
  float ma[4], la[4], mb[4], lb_[4];
#pragma unroll
  for (int j = 0; j < 4; ++j) {
    oa[j] = f32x4{0.f, 0.f, 0.f, 0.f};
    ob[j] = f32x4{0.f, 0.f, 0.f, 0.f};
    ma[j] = -1e30f; la[j] = 0.f; mb[j] = -1e30f; lb_[j] = 0.f;
  }

  auto process = [&](const s16x8& q0f, const s16x8& q1f, f32x4 (&o)[4],
                     float (&m_)[4], float (&l_)[4], int tq0, bool diag,
                     int kt) {
    // QK^T: S[16q x 64k], C/D layout col=key (fr), row=q (crow+j)
    f32x4 sv[4];
#pragma unroll
    for (int sub = 0; sub < 4; ++sub) {
      s16x8 b0 = *(const s16x8*)&ks[(sub * 16 + fr) * AP + fo];
      s16x8 b1 = *(const s16x8*)&ks[(sub * 16 + fr) * AP + 32 + fo];
      f32x4 acc = f32x4{0.f, 0.f, 0.f, 0.f};
      acc = __builtin_amdgcn_mfma_f32_16x16x32_bf16(q0f, b0, acc, 0, 0, 0);
      acc = __builtin_amdgcn_mfma_f32_16x16x32_bf16(q1f, b1, acc, 0, 0, 0);
      sv[sub] = acc;
    }
    if (diag) {
      const int wq0 = tq0 + wave * 16;
#pragma unroll
      for (int sub = 0; sub < 4; ++sub) {
        const int key = kt + sub * 16 + fr;
#pragma unroll
        for (int j = 0; j < 4; ++j)
          if (key > wq0 + crow + j) sv[sub][j] = -1e30f;
      }
    }
    // online softmax with T13 defer-max (THR = 8 exp2-units)
    float corr[4];
    bool anyresc = false;
#pragma unroll
    for (int j = 0; j < 4; ++j) {
      float t = fmaxf(fmaxf(sv[0][j], sv[1][j]), fmaxf(sv[2][j], sv[3][j]));
#pragma unroll
      for (int msk = 1; msk <= 8; msk <<= 1) t = fmaxf(t, __shfl_xor(t, msk));
      const bool resc = t > m_[j] + 8.0f;
      corr[j] = resc ? exp2f(m_[j] - t) : 1.0f;
      if (resc) m_[j] = t;
      anyresc = anyresc || resc;
    }
    float rs[4] = {0.f, 0.f, 0.f, 0.f};
#pragma unroll
    for (int sub = 0; sub < 4; ++sub) {
#pragma unroll
      for (int j = 0; j < 4; ++j) {
        float p = exp2f(sv[sub][j] - m_[j]);
        rs[j] += p;
        ps[wave][(crow + j) * AP + sub * 16 + fr] = __float2bfloat16(p);
      }
    }
#pragma unroll
    for (int j = 0; j < 4; ++j) {
#pragma unroll
      for (int msk = 1; msk <= 8; msk <<= 1) rs[j] += __shfl_xor(rs[j], msk);
      l_[j] = l_[j] * corr[j] + rs[j];
    }
    if (__any(anyresc)) {
#pragma unroll
      for (int ds = 0; ds < 4; ++ds)
#pragma unroll
        for (int j = 0; j < 4; ++j) o[ds][j] *= corr[j];
    }
    s16x8 pf0 = *(const s16x8*)&ps[wave][fr * AP + fo];
    s16x8 pf1 = *(const s16x8*)&ps[wave][fr * AP + 32 + fo];
#pragma unroll
    for (int ds = 0; ds < 4; ++ds) {
      s16x8 v0 = *(const s16x8*)&vt[(ds * 16 + fr) * AP + fo];
      s16x8 v1 = *(const s16x8*)&vt[(ds * 16 + fr) * AP + 32 + fo];
      o[ds] = __builtin_amdgcn_mfma_f32_16x16x32_bf16(pf0, v0, o[ds], 0, 0, 0);
      o[ds] = __builtin_amdgcn_mfma_f32_16x16x32_bf16(pf1, v1, o[ds], 0, 0, 0);
    }
  };

  for (int kt = 0; kt <= qb0; kt += 64) {
    __syncthreads();
#pragma unroll
    for (int j = 0; j < 2; ++j) {
      int c = j * 256 + tid;
      int key = c >> 3, d0 = (c & 7) * 8;
      s16x8 kv = *(const s16x8*)(kb + (size_t)(kt + key) * ldq + d0);
      *(s16x8*)&ks[key * AP + d0] = kv;
    }
#pragma unroll
    for (int j = 0; j < 2; ++j) {
      int d0 = (wave * 2 + j) * 8;
      s16x8 vv = *(const s16x8*)(vb + (size_t)(kt + lane) * ldq + d0);
#pragma unroll
      for (int i = 0; i < 8; ++i)
        vt[(d0 + i) * AP + lane] = ((const __hip_bfloat16*)&vv)[i];
    }
    __syncthreads();

    if (kt <= qa0) process(qfa0, qfa1, oa, ma, la, qa0, kt == qa0, kt);
    process(qfb0, qfb1, ob, mb, lb_, qb0, kt == qb0, kt);
  }

#pragma unroll
  for (int j = 0; j < 4; ++j) {
    const float inva = 1.0f / la[j];
    const float invb = 1.0f / lb_[j];
    __hip_bfloat16* ya =
        y + (size_t)(b * T + qa0 + wave * 16 + crow + j) * N_EMBD + h * HEAD_DIM;
    __hip_bfloat16* yb =
        y + (size_t)(b * T + qb0 + wave * 16 + crow + j) * N_EMBD + h * HEAD_DIM;
#pragma unroll
    for (int ds = 0; ds < 4; ++ds) {
      ya[ds * 16 + fr] = __float2bfloat16(oa[ds][j] * inva);
      yb[ds * 16 + fr] = __float2bfloat16(ob[ds][j] * invb);
    }
  }
}

// ---------------- launch ----------------
extern "C" void kernel_launch(void* const* d_in, const int* in_sizes, int n_in,
                              void* d_out, int out_size, void* d_ws,
                              size_t ws_size, hipStream_t stream) {
  const int B = 4, T = 2048, C = N_EMBD;
  const int M = B * T;  // 8192

  const float* x      = (const float*)d_in[0];
  const float* ln1_g  = (const float*)d_in[1];
  const float* ln1_b  = (const float*)d_in[2];
  const float* attn_w = (const float*)d_in[3];
  const float* attn_b = (const float*)d_in[4];
  const float* proj_w = (const float*)d_in[5];
  const float* proj_b = (const float*)d_in[6];
  const float* ln2_g  = (const float*)d_in[7];
  const float* ln2_b  = (const float*)d_in[8];
  const float* fc_w   = (const float*)d_in[9];
  const float* fc_b   = (const float*)d_in[10];
  const float* fc2_w  = (const float*)d_in[11];
  const float* fc2_b  = (const float*)d_in[12];
  float* out = (float*)d_out;

  char* p = (char*)d_ws;
  size_t off = 0;
  auto take = [&](size_t bytes) -> void* {
    void* q = p + off;
    off += (bytes + 1023) & ~(size_t)1023;
    return q;
  };

  __hip_bfloat16* wqkv  = (__hip_bfloat16*)take((size_t)3 * C * C * 2);
  __hip_bfloat16* wproj = (__hip_bfloat16*)take((size_t)C * C * 2);
  __hip_bfloat16* wfc   = (__hip_bfloat16*)take((size_t)4 * C * C * 2);
  __hip_bfloat16* wfc2  = (__hip_bfloat16*)take((size_t)4 * C * C * 2);
  __hip_bfloat16* hbuf  = (__hip_bfloat16*)take((size_t)M * C * 2);
  __hip_bfloat16* big   = (__hip_bfloat16*)take((size_t)M * 4 * C * 2);
  __hip_bfloat16* ybuf  = (__hip_bfloat16*)take((size_t)M * C * 2);
  float*          x1    = (float*)take((size_t)M * C * 4);

  {
    const int n0 = 3 * C * C, n1 = C * C, n2 = 4 * C * C, n3 = 4 * C * C;
    const int ntot = n0 + n1 + n2 + n3;
    cvt4_kernel<<<(ntot + 255) / 256, 256, 0, stream>>>(
        attn_w, wqkv, proj_w, wproj, fc_w, wfc, fc2_w, wfc2, n0, n1, n2, n3);
  }

  ln_kernel<<<M, 256, 0, stream>>>(x, ln1_g, ln1_b, hbuf);
  gemm_bt<0><<<dim3(3 * C / TILE_N, M / TILE_M), 256, 0, stream>>>(
      hbuf, wqkv, attn_b, nullptr, big, nullptr, M, 3 * C, C);
  attn_mfma<<<dim3(T / 128, B * N_HEADS), 256, 0, stream>>>(big, ybuf, T);
  gemm_bt<2><<<dim3(C / TILE_N, M / TILE_M), 256, 0, stream>>>(
      ybuf, wproj, proj_b, x, nullptr, x1, M, C, C);
  ln_kernel<<<M, 256, 0, stream>>>(x1, ln2_g, ln2_b, hbuf);
  gemm_bt<1><<<dim3(4 * C / TILE_N, M / TILE_M), 256, 0, stream>>>(
      hbuf, wfc, fc_b, nullptr, big, nullptr, M, 4 * C, C);
  gemm_bt<2><<<dim3(C / TILE_N, M / TILE_M), 256, 0, stream>>>(
      big, wfc2, fc2_b, x1, nullptr, out, M, C, 4 * C);
}